// Round 4
// baseline (73.480 us; speedup 1.0000x reference)
//
#include <hip/hip_runtime.h>
#include <hip/hip_bf16.h>

typedef __bf16 bf16x8 __attribute__((ext_vector_type(8)));
typedef __bf16 bf16x4 __attribute__((ext_vector_type(4)));
typedef float  f32x4  __attribute__((ext_vector_type(4)));

static constexpr int E    = 1965;   // J*D + J*3
static constexpr int KF   = 1920;   // J*D
static constexpr int NJ   = 15;
static constexpr int NCLS = 68;
static constexpr int NPAD = 80;     // 5 tiles of 16
static constexpr int NT   = 5;
static constexpr int NS   = 60;     // k-steps of 32
static constexpr int AST  = 1928;   // A-tile LDS row stride (bf16)
static constexpr int PDB  = 8;      // B-fragment prefetch depth
static constexpr int PDA  = 4;      // A-fragment prefetch depth

// ws layout:
//   pnf: [NT][NS][64][8] __bf16  = 307200 B
//   pa : [NPAD][45] float        = 14400 B
static constexpr size_t PNF_BYTES = (size_t)NT * NS * 64 * 8 * 2;

// ---------------- kernel 1: normalize W -> bf16 fragments + angle extract ----
__global__ __launch_bounds__(256) void prep_kernel(const float* __restrict__ W,
                                                   __bf16* __restrict__ pnf,
                                                   float* __restrict__ pa) {
    const int n = blockIdx.x;      // 0..79
    const int t = threadIdx.x;     // 0..255
    float v[8];
    float ss = 0.f;
    if (n < NCLS && t < 240) {
        const float* src = W + (size_t)n * E + 8 * t;
        #pragma unroll
        for (int i = 0; i < 8; ++i) { v[i] = src[i]; ss += v[i] * v[i]; }
    } else {
        #pragma unroll
        for (int i = 0; i < 8; ++i) v[i] = 0.f;
    }
    #pragma unroll
    for (int off = 32; off >= 1; off >>= 1) ss += __shfl_xor(ss, off);
    __shared__ float rbuf[4];
    if ((t & 63) == 0) rbuf[t >> 6] = ss;
    __syncthreads();
    const float total = rbuf[0] + rbuf[1] + rbuf[2] + rbuf[3];
    const float rnorm = 1.f / fmaxf(sqrtf(total), 1e-12f);

    if (t < 240) {
        bf16x8 o;
        #pragma unroll
        for (int i = 0; i < 8; ++i) o[i] = (__bf16)(v[i] * rnorm);
        const int s = t >> 2, g = t & 3;
        const int lane = (n & 15) + 16 * g;
        const size_t off = (((size_t)(n >> 4) * NS + s) * 64 + lane) * 8;
        *(bf16x8*)(pnf + off) = o;
    }
    if (t < 45) {
        pa[n * 45 + t] = (n < NCLS) ? W[(size_t)n * E + KF + t] : 0.f;
    }
}

// ---------------- kernel 2: fused GEMM + norm + angle softmax ----------------
__global__ __launch_bounds__(320, 3) void cos_kernel(const float* __restrict__ emb,
                                                     const __bf16* __restrict__ pnf,
                                                     const float* __restrict__ pa,
                                                     float* __restrict__ out) {
    __shared__ __bf16 A[16][AST];          // 61,696 B — whole A tile, single buffer
    __shared__ __bf16 pal[NPAD][52];       //  8,320 B
    __shared__ float  xa[16][48];          //  3,072 B
    __shared__ float  sp[320];
    __shared__ float  srow[16];

    const int tid = threadIdx.x;
    const int m0  = blockIdx.x * 16;

    // ---- angle staging (ordered by barrier 1) ----
    for (int idx = tid; idx < 16 * 45; idx += 320) {
        const int r = idx / 45, c = idx - r * 45;
        xa[r][c] = emb[(size_t)(m0 + r) * E + KF + c];
    }
    for (int idx = tid; idx < NPAD * 45; idx += 320) {
        const int n = idx / 45, c = idx - n * 45;
        pal[n][c] = (__bf16)pa[idx];
    }

    // ---- A staging: issue ALL 24 dwordx4 loads back-to-back (24-deep MLP) ----
    const int row = tid / 20;
    const int sc  = tid % 20;
    const float* arow = emb + (size_t)(m0 + row) * E + 4 * sc;
    f32x4 av[24];
    #pragma unroll
    for (int i = 0; i < 24; ++i)
        __builtin_memcpy(&av[i], arow + 80 * i, 16);

    float ssq = 0.f;
    #pragma unroll
    for (int i = 0; i < 24; ++i) {
        bf16x4 o;
        #pragma unroll
        for (int q = 0; q < 4; ++q) {
            const float x = av[i][q];
            ssq += x * x;
            o[q] = (__bf16)x;
        }
        *(bf16x4*)&A[row][4 * sc + 80 * i] = o;
    }
    sp[tid] = ssq;
    __syncthreads();                       // barrier 1: A + sp + angles visible

    // ssq reduction hides in the K-loop shadow
    if (tid < 16) {
        float s = 0.f;
        #pragma unroll
        for (int i = 0; i < 20; ++i) s += sp[tid * 20 + i];
        srow[tid] = s;
    }

    // ---- barrier-free K-loop with explicit rolling prefetch ----
    const int w  = tid >> 6;     // N-tile 0..4
    const int l  = tid & 63;
    const int lr = l & 15;       // A row / B col within tile
    const int lg = l >> 4;       // k-group
    const bf16x8* bp = (const bf16x8*)pnf + (size_t)w * NS * 64 + l;
    const __bf16* ab = &A[lr][8 * lg];

    f32x4 acc[NJ];
    #pragma unroll
    for (int j = 0; j < NJ; ++j) acc[j] = f32x4{0.f, 0.f, 0.f, 0.f};

    bf16x8 bpf[PDB];
    bf16x8 apf[PDA];
    #pragma unroll
    for (int i = 0; i < PDB; ++i) bpf[i] = bp[i * 64];
    #pragma unroll
    for (int i = 0; i < PDA; ++i) apf[i] = *(const bf16x8*)(ab + 32 * i);

    #pragma unroll
    for (int s = 0; s < NS; ++s) {         // fully unrolled: all indices static
        const bf16x8 b = bpf[s % PDB];
        const bf16x8 a = apf[s % PDA];
        if (s + PDB < NS) bpf[s % PDB] = bp[(s + PDB) * 64];
        if (s + PDA < NS) apf[s % PDA] = *(const bf16x8*)(ab + 32 * (s + PDA));
        acc[s >> 2] = __builtin_amdgcn_mfma_f32_16x16x32_bf16(a, b, acc[s >> 2], 0, 0, 0);
    }
    __syncthreads();                       // barrier 2: srow visible

    // ---- epilogue ----
    const int r0  = lg * 4;      // C/D: row = (lane>>4)*4 + reg, col = lane&15
    const int col = w * 16 + lr;

    float rn[4];
    #pragma unroll
    for (int r = 0; r < 4; ++r)
        rn[r] = 240.f / fmaxf(sqrtf(srow[r0 + r]), 1e-12f);   // 16*15/norm

    float pr[45];
    #pragma unroll
    for (int q = 0; q < 12; ++q) {
        const bf16x4 pv = *(const bf16x4*)&pal[col][4 * q];
        #pragma unroll
        for (int e = 0; e < 4; ++e)
            if (4 * q + e < 45) pr[4 * q + e] = (float)pv[e];
    }

    float num[4] = {0.f, 0.f, 0.f, 0.f};
    float den[4] = {0.f, 0.f, 0.f, 0.f};
    #pragma unroll
    for (int r = 0; r < 4; ++r) {
        f32x4 xr[12];
        #pragma unroll
        for (int q = 0; q < 12; ++q)
            xr[q] = *(const f32x4*)&xa[r0 + r][4 * q];
        #pragma unroll
        for (int j = 0; j < NJ; ++j) {
            const float d0 = xr[(3 * j + 0) >> 2][(3 * j + 0) & 3] - pr[3 * j + 0];
            const float d1 = xr[(3 * j + 1) >> 2][(3 * j + 1) & 3] - pr[3 * j + 1];
            const float d2 = xr[(3 * j + 2) >> 2][(3 * j + 2) & 3] - pr[3 * j + 2];
            const float dist = sqrtf(d0 * d0 + d1 * d1 + d2 * d2);
            const float e = __expf(dist * 0.005f);   // exponents in [0, ~0.05]
            den[r] += e;
            num[r] += e * acc[j][r];
        }
    }

    if (col < NCLS) {
        #pragma unroll
        for (int r = 0; r < 4; ++r)
            out[(size_t)(m0 + r0 + r) * NCLS + col] = rn[r] * num[r] / den[r];
    }
}

extern "C" void kernel_launch(void* const* d_in, const int* in_sizes, int n_in,
                              void* d_out, int out_size, void* d_ws, size_t ws_size,
                              hipStream_t stream) {
    const float* emb = (const float*)d_in[0];
    const float* W   = (const float*)d_in[1];
    float* out = (float*)d_out;
    __bf16* pnf = (__bf16*)d_ws;
    float*  pa  = (float*)((char*)d_ws + PNF_BYTES);
    const int B = in_sizes[0] / E;           // 16384

    prep_kernel<<<NPAD, 256, 0, stream>>>(W, pnf, pa);
    cos_kernel<<<B / 16, 320, 0, stream>>>(emb, pnf, pa, out);
}